// Round 1
// baseline (4729.640 us; speedup 1.0000x reference)
//
#include <hip/hip_runtime.h>
#include <hip/hip_bf16.h>

#define MC 4096
#define DD 128
#define NHH 4
#define DH 32
#define FFD 256
#define NS 3

__device__ __forceinline__ int getM(int s, const int* M0, const int* M1, const int* M2) {
    return (s == 0) ? *M0 : (s == 1) ? *M1 : *M2;
}

// ---------------- scatter-add all 3 scales, h read once ----------------
__global__ void k_scatter(const float* __restrict__ h,
                          const int* __restrict__ inv0,
                          const int* __restrict__ inv1,
                          const int* __restrict__ inv2,
                          float* __restrict__ macro, float* __restrict__ counts, int N)
{
    long long idx = (long long)blockIdx.x * blockDim.x + threadIdx.x;
    long long total = (long long)N * DD;
    if (idx >= total) return;
    int n = (int)(idx >> 7);
    int d = (int)(idx & 127);
    float v = h[idx];
    int i0 = inv0[n], i1 = inv1[n], i2 = inv2[n];
    atomicAdd(&macro[(size_t)0 * MC * DD + (size_t)i0 * DD + d], v);
    atomicAdd(&macro[(size_t)1 * MC * DD + (size_t)i1 * DD + d], v);
    atomicAdd(&macro[(size_t)2 * MC * DD + (size_t)i2 * DD + d], v);
    if (d == 0) {
        atomicAdd(&counts[0 * MC + i0], 1.0f);
        atomicAdd(&counts[1 * MC + i1], 1.0f);
        atomicAdd(&counts[2 * MC + i2], 1.0f);
    }
}

// ---------------- divide by clamped counts ----------------
__global__ void k_finalize(float* __restrict__ macro, const float* __restrict__ counts,
                           const int* M0, const int* M1, const int* M2)
{
    int idx = blockIdx.x * blockDim.x + threadIdx.x;  // < NS*MC*DD
    int s = idx / (MC * DD);
    int r = (idx >> 7) & (MC - 1);
    if (r >= getM(s, M0, M1, M2)) return;
    float c = counts[s * MC + r];
    macro[idx] /= fmaxf(c, 1.0f);
}

// ---------------- B0T[k][d] = Wf[d][k] ----------------
__global__ void k_b0t(const float* __restrict__ Wf, float* __restrict__ B0T)
{
    int idx = blockIdx.x * 256 + threadIdx.x;  // 16384
    int k = idx >> 7, d = idx & 127;
    B0T[idx] = Wf[(size_t)d * (4 * DD) + k];
}

// ---------------- qkv = macro @ Wqkv[s].T + bqkv[s], 8 rows/block ----------------
__global__ void k_qkv(const float* __restrict__ macro, const float* __restrict__ Wqkv,
                      const float* __restrict__ bqkv, float* __restrict__ qkv,
                      const int* M0, const int* M1, const int* M2)
{
    int s = blockIdx.y;
    int Ms = getM(s, M0, M1, M2);
    int row0 = blockIdx.x * 8;
    if (row0 >= Ms) return;
    __shared__ __align__(16) float mac[8][DD];
    int tid = threadIdx.x;
    for (int e = tid; e < 8 * DD; e += 256) {
        int r = e >> 7, d = e & 127;
        int row = row0 + r;
        mac[r][d] = (row < Ms) ? macro[(size_t)s * MC * DD + (size_t)row * DD + d] : 0.0f;
    }
    __syncthreads();
    for (int j = tid; j < 3 * DD; j += 256) {
        const float* w = Wqkv + ((size_t)s * 3 * DD + j) * DD;
        float b = bqkv[s * 3 * DD + j];
        float acc[8];
#pragma unroll
        for (int r = 0; r < 8; ++r) acc[r] = b;
        for (int k = 0; k < DD; k += 4) {
            float4 w4 = *(const float4*)(w + k);
#pragma unroll
            for (int r = 0; r < 8; ++r) {
                float4 m4 = *(const float4*)&mac[r][k];
                acc[r] += w4.x * m4.x + w4.y * m4.y + w4.z * m4.z + w4.w * m4.w;
            }
        }
        for (int r = 0; r < 8; ++r) {
            int row = row0 + r;
            if (row < Ms) qkv[((size_t)s * MC + row) * (3 * DD) + j] = acc[r];
        }
    }
}

// ---------------- flash-style attention, 64-q tile/block, fp32 ----------------
__global__ __launch_bounds__(256) void k_attn(const float* __restrict__ qkv,
                                              float* __restrict__ attno,
                                              const int* M0, const int* M1, const int* M2)
{
    int s = blockIdx.z;
    int head = blockIdx.y;
    int Ms = getM(s, M0, M1, M2);
    int q0 = blockIdx.x * 64;
    if (q0 >= Ms) return;

    __shared__ __align__(16) float qs[64][36];
    __shared__ __align__(16) float ks[64][36];
    __shared__ __align__(16) float vs[64][36];
    __shared__ float ps[64][66];
    __shared__ float m_s[64], l_s[64], a_s[64];

    int tid = threadIdx.x;
    const float* base = qkv + (size_t)s * MC * 3 * DD;

    for (int e = tid; e < 64 * 8; e += 256) {
        int r = e >> 3, qq = e & 7;
        int row = q0 + r;
        float4 v4 = make_float4(0.f, 0.f, 0.f, 0.f);
        if (row < Ms) v4 = *(const float4*)(base + (size_t)row * 3 * DD + head * DH + qq * 4);
        *(float4*)&qs[r][qq * 4] = v4;
    }
    if (tid < 64) { m_s[tid] = -1e30f; l_s[tid] = 0.0f; }

    float4 o0 = make_float4(0.f, 0.f, 0.f, 0.f);
    float4 o1 = make_float4(0.f, 0.f, 0.f, 0.f);
    int qi = tid >> 2, sub = tid & 3;
    int nchunks = (Ms + 63) >> 6;
    const float scale = 0.1767766952966369f;  // 1/sqrt(32)

    for (int ch = 0; ch < nchunks; ++ch) {
        int kb = ch * 64;
        __syncthreads();  // protect ks/vs/ps from previous iteration readers
        for (int e = tid; e < 64 * 8; e += 256) {
            int r = e >> 3, qq = e & 7;
            int key = kb + r;
            float4 kv4 = make_float4(0.f, 0.f, 0.f, 0.f);
            float4 vv4 = make_float4(0.f, 0.f, 0.f, 0.f);
            if (key < Ms) {
                kv4 = *(const float4*)(base + (size_t)key * 3 * DD + DD + head * DH + qq * 4);
                vv4 = *(const float4*)(base + (size_t)key * 3 * DD + 2 * DD + head * DH + qq * 4);
            }
            *(float4*)&ks[r][qq * 4] = kv4;
            *(float4*)&vs[r][qq * 4] = vv4;
        }
        __syncthreads();
        {   // scores: 4x4 block per thread
            int qg = (tid & 15) * 4;
            int kg = (tid >> 4) * 4;
            float scr[4][4];
#pragma unroll
            for (int i = 0; i < 4; ++i)
#pragma unroll
                for (int j = 0; j < 4; ++j) scr[i][j] = 0.f;
#pragma unroll
            for (int dq = 0; dq < 8; ++dq) {
                float4 qv[4], kv[4];
#pragma unroll
                for (int i = 0; i < 4; ++i) qv[i] = *(const float4*)&qs[qg + i][dq * 4];
#pragma unroll
                for (int j = 0; j < 4; ++j) kv[j] = *(const float4*)&ks[kg + j][dq * 4];
#pragma unroll
                for (int i = 0; i < 4; ++i)
#pragma unroll
                    for (int j = 0; j < 4; ++j)
                        scr[i][j] += qv[i].x * kv[j].x + qv[i].y * kv[j].y +
                                     qv[i].z * kv[j].z + qv[i].w * kv[j].w;
            }
#pragma unroll
            for (int i = 0; i < 4; ++i)
#pragma unroll
                for (int j = 0; j < 4; ++j) {
                    int kglob = kb + kg + j;
                    ps[qg + i][kg + j] = (kglob < Ms) ? scr[i][j] * scale : -1e30f;
                }
        }
        __syncthreads();
        {   // online softmax update: 4 threads per row
            float mold = m_s[qi];
            float lmax = -1e30f;
            for (int t = 0; t < 16; ++t) lmax = fmaxf(lmax, ps[qi][sub * 16 + t]);
            lmax = fmaxf(lmax, __shfl_xor(lmax, 1));
            lmax = fmaxf(lmax, __shfl_xor(lmax, 2));
            float mnew = fmaxf(mold, lmax);
            float lsum = 0.f;
            for (int t = 0; t < 16; ++t) {
                float e = __expf(ps[qi][sub * 16 + t] - mnew);
                ps[qi][sub * 16 + t] = e;
                lsum += e;
            }
            lsum += __shfl_xor(lsum, 1);
            lsum += __shfl_xor(lsum, 2);
            if (sub == 0) {
                m_s[qi] = mnew;
                float alpha = __expf(mold - mnew);
                l_s[qi] = l_s[qi] * alpha + lsum;
                a_s[qi] = alpha;
            }
        }
        __syncthreads();
        {   // PV accumulate into registers
            float alpha = a_s[qi];
            o0.x *= alpha; o0.y *= alpha; o0.z *= alpha; o0.w *= alpha;
            o1.x *= alpha; o1.y *= alpha; o1.z *= alpha; o1.w *= alpha;
            int d0 = sub * 4, d1 = (sub + 4) * 4;
            for (int key = 0; key < 64; ++key) {
                float p = ps[qi][key];
                float4 va = *(const float4*)&vs[key][d0];
                float4 vb = *(const float4*)&vs[key][d1];
                o0.x += p * va.x; o0.y += p * va.y; o0.z += p * va.z; o0.w += p * va.w;
                o1.x += p * vb.x; o1.y += p * vb.y; o1.z += p * vb.z; o1.w += p * vb.w;
            }
        }
    }
    __syncthreads();
    if (q0 + qi < Ms) {
        float inv = 1.0f / fmaxf(l_s[qi], 1e-30f);
        size_t orow = ((size_t)s * MC + q0 + qi) * DD + head * DH;
        float4 r0 = make_float4(o0.x * inv, o0.y * inv, o0.z * inv, o0.w * inv);
        float4 r1 = make_float4(o1.x * inv, o1.y * inv, o1.z * inv, o1.w * inv);
        *(float4*)(attno + orow + sub * 4) = r0;
        *(float4*)(attno + orow + (sub + 4) * 4) = r1;
    }
}

// ---------------- x1 = LN1(macro + attno @ Wo.T + bo) ----------------
__global__ void k_ln1(const float* __restrict__ macro, const float* __restrict__ attno,
                      const float* __restrict__ Wo, const float* __restrict__ bo,
                      const float* __restrict__ g, const float* __restrict__ b,
                      float* __restrict__ x1,
                      const int* M0, const int* M1, const int* M2)
{
    int s = blockIdx.y;
    int Ms = getM(s, M0, M1, M2);
    int m = blockIdx.x;
    if (m >= Ms) return;
    __shared__ __align__(16) float os[DD];
    __shared__ float red[4];
    int d = threadIdx.x;  // 128
    size_t row = (size_t)s * MC + m;
    os[d] = attno[row * DD + d];
    __syncthreads();
    const float* w = Wo + ((size_t)s * DD + d) * DD;
    float acc = bo[s * DD + d];
    for (int k = 0; k < DD; k += 4) {
        float4 w4 = *(const float4*)(w + k);
        float4 m4 = *(const float4*)&os[k];
        acc += w4.x * m4.x + w4.y * m4.y + w4.z * m4.z + w4.w * m4.w;
    }
    float xin = macro[row * DD + d] + acc;
    float sum = xin, sq = xin * xin;
    for (int off = 32; off >= 1; off >>= 1) { sum += __shfl_xor(sum, off); sq += __shfl_xor(sq, off); }
    if ((d & 63) == 0) { red[d >> 6] = sum; red[2 + (d >> 6)] = sq; }
    __syncthreads();
    sum = red[0] + red[1]; sq = red[2] + red[3];
    float mean = sum * (1.0f / DD);
    float var = fmaxf(sq * (1.0f / DD) - mean * mean, 0.0f);
    float xh = (xin - mean) * rsqrtf(var + 1e-5f);
    x1[row * DD + d] = xh * g[s * DD + d] + b[s * DD + d];
}

// ---------------- x2 = LN2(x1 + relu(x1@W1.T+b1)@W2.T + b2) ----------------
__global__ void k_ffn(const float* __restrict__ x1,
                      const float* __restrict__ W1, const float* __restrict__ b1,
                      const float* __restrict__ W2, const float* __restrict__ b2,
                      const float* __restrict__ g, const float* __restrict__ bb,
                      float* __restrict__ x2,
                      const int* M0, const int* M1, const int* M2)
{
    int s = blockIdx.y;
    int Ms = getM(s, M0, M1, M2);
    int m = blockIdx.x;
    if (m >= Ms) return;
    __shared__ __align__(16) float xr[DD];
    __shared__ __align__(16) float ts[FFD];
    __shared__ float red[8];
    int tid = threadIdx.x;  // 256
    size_t row = (size_t)s * MC + m;
    if (tid < DD) xr[tid] = x1[row * DD + tid];
    __syncthreads();
    {
        const float* w = W1 + ((size_t)s * FFD + tid) * DD;
        float acc = b1[s * FFD + tid];
        for (int k = 0; k < DD; k += 4) {
            float4 w4 = *(const float4*)(w + k);
            float4 m4 = *(const float4*)&xr[k];
            acc += w4.x * m4.x + w4.y * m4.y + w4.z * m4.z + w4.w * m4.w;
        }
        ts[tid] = fmaxf(acc, 0.0f);
    }
    __syncthreads();
    float xin = 0.0f;
    if (tid < DD) {
        const float* w = W2 + ((size_t)s * DD + tid) * FFD;
        float acc = b2[s * DD + tid];
        for (int k = 0; k < FFD; k += 4) {
            float4 w4 = *(const float4*)(w + k);
            float4 m4 = *(const float4*)&ts[k];
            acc += w4.x * m4.x + w4.y * m4.y + w4.z * m4.z + w4.w * m4.w;
        }
        xin = xr[tid] + acc;
    }
    float sum = xin, sq = xin * xin;
    for (int off = 32; off >= 1; off >>= 1) { sum += __shfl_xor(sum, off); sq += __shfl_xor(sq, off); }
    if ((tid & 63) == 0) { red[tid >> 6] = sum; red[4 + (tid >> 6)] = sq; }
    __syncthreads();
    sum = red[0] + red[1] + red[2] + red[3];
    sq = red[4] + red[5] + red[6] + red[7];
    float mean = sum * (1.0f / DD);
    float var = fmaxf(sq * (1.0f / DD) - mean * mean, 0.0f);
    if (tid < DD) {
        float xh = (xin - mean) * rsqrtf(var + 1e-5f);
        x2[row * DD + tid] = xh * g[s * DD + tid] + bb[s * DD + tid];
    }
}

// ---------------- y_s = x2_s @ Wf[:, 128*(s+1):128*(s+2)].T ----------------
__global__ void k_yproj(const float* __restrict__ x2, const float* __restrict__ Wf,
                        float* __restrict__ y,
                        const int* M0, const int* M1, const int* M2)
{
    int s = blockIdx.y;
    int Ms = getM(s, M0, M1, M2);
    int m = blockIdx.x;
    if (m >= Ms) return;
    __shared__ __align__(16) float xr[DD];
    int d = threadIdx.x;  // 128
    size_t row = (size_t)s * MC + m;
    xr[d] = x2[row * DD + d];
    __syncthreads();
    const float* w = Wf + (size_t)d * (4 * DD) + (s + 1) * DD;
    float acc = 0.0f;
    for (int k = 0; k < DD; k += 4) {
        float4 w4 = *(const float4*)(w + k);
        float4 m4 = *(const float4*)&xr[k];
        acc += w4.x * m4.x + w4.y * m4.y + w4.z * m4.z + w4.w * m4.w;
    }
    y[row * DD + d] = acc;
}

// ---------------- out = h@B0 + y0[inv0] + y1[inv1] + y2[inv2] + bf ----------------
__global__ __launch_bounds__(256) void k_final(const float* __restrict__ h,
                                               const float* __restrict__ B0T,
                                               const float* __restrict__ y,
                                               const int* __restrict__ inv0,
                                               const int* __restrict__ inv1,
                                               const int* __restrict__ inv2,
                                               const float* __restrict__ bf,
                                               float* __restrict__ out, int N)
{
    __shared__ __align__(16) float hs[64][132];
    int tid = threadIdx.x;
    int ntiles = (N + 63) >> 6;
    const float* y0 = y;
    const float* y1 = y + (size_t)MC * DD;
    const float* y2 = y + (size_t)2 * MC * DD;
    for (int t = blockIdx.x; t < ntiles; t += gridDim.x) {
        int pb = t * 64;
        __syncthreads();
        for (int fq = tid; fq < 64 * 32; fq += 256) {
            int p = fq >> 5, q = fq & 31;
            float4 v4 = make_float4(0.f, 0.f, 0.f, 0.f);
            if (pb + p < N) v4 = *(const float4*)(h + ((size_t)(pb + p)) * DD + q * 4);
            *(float4*)&hs[p][q * 4] = v4;
        }
        __syncthreads();
        int pg = tid & 15, dg = tid >> 4;
        int d0 = dg * 8;
        float4 a0[4], a1[4];
#pragma unroll
        for (int i = 0; i < 4; ++i) {
            a0[i] = make_float4(0.f, 0.f, 0.f, 0.f);
            a1[i] = make_float4(0.f, 0.f, 0.f, 0.f);
        }
        for (int k = 0; k < DD; k += 4) {
            float4 h4[4];
#pragma unroll
            for (int i = 0; i < 4; ++i) h4[i] = *(const float4*)&hs[pg + 16 * i][k];
#pragma unroll
            for (int kk = 0; kk < 4; ++kk) {
                float4 ba = *(const float4*)(B0T + (size_t)(k + kk) * DD + d0);
                float4 bb = *(const float4*)(B0T + (size_t)(k + kk) * DD + d0 + 4);
#pragma unroll
                for (int i = 0; i < 4; ++i) {
                    float hv = (kk == 0) ? h4[i].x : (kk == 1) ? h4[i].y : (kk == 2) ? h4[i].z : h4[i].w;
                    a0[i].x += hv * ba.x; a0[i].y += hv * ba.y; a0[i].z += hv * ba.z; a0[i].w += hv * ba.w;
                    a1[i].x += hv * bb.x; a1[i].y += hv * bb.y; a1[i].z += hv * bb.z; a1[i].w += hv * bb.w;
                }
            }
        }
        float4 bf0 = *(const float4*)(bf + d0);
        float4 bf1 = *(const float4*)(bf + d0 + 4);
#pragma unroll
        for (int i = 0; i < 4; ++i) {
            int p = pb + pg + 16 * i;
            if (p >= N) continue;
            int i0 = inv0[p], i1 = inv1[p], i2 = inv2[p];
            float4 g0 = *(const float4*)(y0 + (size_t)i0 * DD + d0);
            float4 g0b = *(const float4*)(y0 + (size_t)i0 * DD + d0 + 4);
            float4 g1 = *(const float4*)(y1 + (size_t)i1 * DD + d0);
            float4 g1b = *(const float4*)(y1 + (size_t)i1 * DD + d0 + 4);
            float4 g2 = *(const float4*)(y2 + (size_t)i2 * DD + d0);
            float4 g2b = *(const float4*)(y2 + (size_t)i2 * DD + d0 + 4);
            float4 r0 = make_float4(a0[i].x + g0.x + g1.x + g2.x + bf0.x,
                                    a0[i].y + g0.y + g1.y + g2.y + bf0.y,
                                    a0[i].z + g0.z + g1.z + g2.z + bf0.z,
                                    a0[i].w + g0.w + g1.w + g2.w + bf0.w);
            float4 r1 = make_float4(a1[i].x + g0b.x + g1b.x + g2b.x + bf1.x,
                                    a1[i].y + g0b.y + g1b.y + g2b.y + bf1.y,
                                    a1[i].z + g0b.z + g1b.z + g2b.z + bf1.z,
                                    a1[i].w + g0b.w + g1b.w + g2b.w + bf1.w);
            *(float4*)(out + (size_t)p * DD + d0) = r0;
            *(float4*)(out + (size_t)p * DD + d0 + 4) = r1;
        }
    }
}

extern "C" void kernel_launch(void* const* d_in, const int* in_sizes, int n_in,
                              void* d_out, int out_size, void* d_ws, size_t ws_size,
                              hipStream_t stream) {
    (void)n_in; (void)out_size; (void)ws_size;
    const float* h   = (const float*)d_in[0];
    const int* inv0  = (const int*)d_in[2];
    const int* inv1  = (const int*)d_in[3];
    const int* inv2  = (const int*)d_in[4];
    const int* M0    = (const int*)d_in[5];
    const int* M1    = (const int*)d_in[6];
    const int* M2    = (const int*)d_in[7];
    const float* Wqkv = (const float*)d_in[8];
    const float* bqkv = (const float*)d_in[9];
    const float* Wo   = (const float*)d_in[10];
    const float* bo   = (const float*)d_in[11];
    const float* ln1s = (const float*)d_in[12];
    const float* ln1b = (const float*)d_in[13];
    const float* W1   = (const float*)d_in[14];
    const float* b1   = (const float*)d_in[15];
    const float* W2   = (const float*)d_in[16];
    const float* b2   = (const float*)d_in[17];
    const float* ln2s = (const float*)d_in[18];
    const float* ln2b = (const float*)d_in[19];
    const float* Wf   = (const float*)d_in[20];
    const float* bf   = (const float*)d_in[21];
    int N = in_sizes[0] / DD;

    float* ws     = (float*)d_ws;
    float* macro  = ws;                                     // NS*MC*DD
    float* counts = macro + (size_t)NS * MC * DD;           // NS*MC
    float* qkvb   = counts + (size_t)NS * MC;               // NS*MC*3*DD
    float* attno  = qkvb + (size_t)NS * MC * 3 * DD;        // NS*MC*DD
    float* x1     = attno + (size_t)NS * MC * DD;           // NS*MC*DD
    float* x2     = x1 + (size_t)NS * MC * DD;              // NS*MC*DD
    float* yb     = x2 + (size_t)NS * MC * DD;              // NS*MC*DD
    float* B0T    = yb + (size_t)NS * MC * DD;              // DD*DD

    hipMemsetAsync(macro, 0, ((size_t)NS * MC * DD + NS * MC) * sizeof(float), stream);

    long long total = (long long)N * DD;
    int sblocks = (int)((total + 255) / 256);
    k_scatter<<<sblocks, 256, 0, stream>>>(h, inv0, inv1, inv2, macro, counts, N);
    k_finalize<<<(NS * MC * DD) / 256, 256, 0, stream>>>(macro, counts, M0, M1, M2);
    k_b0t<<<64, 256, 0, stream>>>(Wf, B0T);
    k_qkv<<<dim3(MC / 8, NS), 256, 0, stream>>>(macro, Wqkv, bqkv, qkvb, M0, M1, M2);
    k_attn<<<dim3(MC / 64, NHH, NS), 256, 0, stream>>>(qkvb, attno, M0, M1, M2);
    k_ln1<<<dim3(MC, NS), 128, 0, stream>>>(macro, attno, Wo, bo, ln1s, ln1b, x1, M0, M1, M2);
    k_ffn<<<dim3(MC, NS), 256, 0, stream>>>(x1, W1, b1, W2, b2, ln2s, ln2b, x2, M0, M1, M2);
    k_yproj<<<dim3(MC, NS), 128, 0, stream>>>(x2, Wf, yb, M0, M1, M2);
    k_final<<<2048, 256, 0, stream>>>(h, B0T, yb, inv0, inv1, inv2, bf, (float*)d_out, N);
}

// Round 2
// 1313.727 us; speedup vs baseline: 3.6002x; 3.6002x over previous
//
#include <hip/hip_runtime.h>
#include <hip/hip_bf16.h>

#define MC 4096
#define DD 128
#define NHH 4
#define DH 32
#define FFD 256
#define NS 3

__device__ __forceinline__ int getM(int s, const int* M0, const int* M1, const int* M2) {
    return (s == 0) ? *M0 : (s == 1) ? *M1 : *M2;
}

// ---------------- parent maps from inv arrays (nested grids) ----------------
__global__ void k_parent(const int* __restrict__ inv0, const int* __restrict__ inv1,
                         const int* __restrict__ inv2,
                         int* __restrict__ parent10, int* __restrict__ parent21, int N)
{
    int n = blockIdx.x * blockDim.x + threadIdx.x;
    if (n >= N) return;
    parent10[inv0[n]] = inv1[n];   // duplicate writes all agree (grids nest)
    parent21[inv1[n]] = inv2[n];
}

// ---------------- scatter-add scale 0 only ----------------
__global__ void k_scatter0(const float* __restrict__ h,
                           const int* __restrict__ inv0,
                           float* __restrict__ sum0, float* __restrict__ cnt0, int N)
{
    long long idx = (long long)blockIdx.x * blockDim.x + threadIdx.x;
    long long total = (long long)N * DD;
    if (idx >= total) return;
    int n = (int)(idx >> 7);
    int d = (int)(idx & 127);
    float v = h[idx];
    int i0 = inv0[n];
    atomicAdd(&sum0[(size_t)i0 * DD + d], v);
    if (d == 0) atomicAdd(&cnt0[i0], 1.0f);
}

// ---------------- roll coarse sums up the hierarchy ----------------
__global__ void k_rollup(const float* __restrict__ sumSrc, const float* __restrict__ cntSrc,
                         const int* __restrict__ parent,
                         float* __restrict__ sumDst, float* __restrict__ cntDst,
                         const int* __restrict__ Msrc, int cap)
{
    int idx = blockIdx.x * blockDim.x + threadIdx.x;   // < cap*DD
    int v = idx >> 7, d = idx & 127;
    int Ms = *Msrc;
    if (Ms > cap) Ms = cap;
    if (v >= Ms) return;
    int p = parent[v];
    atomicAdd(&sumDst[(size_t)p * DD + d], sumSrc[idx]);
    if (d == 0) atomicAdd(&cntDst[p], cntSrc[v]);
}

// ---------------- divide by clamped counts ----------------
__global__ void k_finalize(float* __restrict__ macro, const float* __restrict__ counts,
                           const int* M0, const int* M1, const int* M2)
{
    int idx = blockIdx.x * blockDim.x + threadIdx.x;  // < NS*MC*DD
    int s = idx / (MC * DD);
    int r = (idx >> 7) & (MC - 1);
    if (r >= getM(s, M0, M1, M2)) return;
    float c = counts[s * MC + r];
    macro[idx] /= fmaxf(c, 1.0f);
}

// ---------------- B0T[k][d] = Wf[d][k] ----------------
__global__ void k_b0t(const float* __restrict__ Wf, float* __restrict__ B0T)
{
    int idx = blockIdx.x * 256 + threadIdx.x;  // 16384
    int k = idx >> 7, d = idx & 127;
    B0T[idx] = Wf[(size_t)d * (4 * DD) + k];
}

// ---------------- qkv = macro @ Wqkv[s].T + bqkv[s], 8 rows/block ----------------
__global__ void k_qkv(const float* __restrict__ macro, const float* __restrict__ Wqkv,
                      const float* __restrict__ bqkv, float* __restrict__ qkv,
                      const int* M0, const int* M1, const int* M2)
{
    int s = blockIdx.y;
    int Ms = getM(s, M0, M1, M2);
    int row0 = blockIdx.x * 8;
    if (row0 >= Ms) return;
    __shared__ __align__(16) float mac[8][DD];
    int tid = threadIdx.x;
    for (int e = tid; e < 8 * DD; e += 256) {
        int r = e >> 7, d = e & 127;
        int row = row0 + r;
        mac[r][d] = (row < Ms) ? macro[(size_t)s * MC * DD + (size_t)row * DD + d] : 0.0f;
    }
    __syncthreads();
    for (int j = tid; j < 3 * DD; j += 256) {
        const float* w = Wqkv + ((size_t)s * 3 * DD + j) * DD;
        float b = bqkv[s * 3 * DD + j];
        float acc[8];
#pragma unroll
        for (int r = 0; r < 8; ++r) acc[r] = b;
        for (int k = 0; k < DD; k += 4) {
            float4 w4 = *(const float4*)(w + k);
#pragma unroll
            for (int r = 0; r < 8; ++r) {
                float4 m4 = *(const float4*)&mac[r][k];
                acc[r] += w4.x * m4.x + w4.y * m4.y + w4.z * m4.z + w4.w * m4.w;
            }
        }
        for (int r = 0; r < 8; ++r) {
            int row = row0 + r;
            if (row < Ms) qkv[((size_t)s * MC + row) * (3 * DD) + j] = acc[r];
        }
    }
}

// ---------------- flash-style attention, 64-q tile/block, fp32 ----------------
__global__ __launch_bounds__(256) void k_attn(const float* __restrict__ qkv,
                                              float* __restrict__ attno,
                                              const int* M0, const int* M1, const int* M2)
{
    int s = blockIdx.z;
    int head = blockIdx.y;
    int Ms = getM(s, M0, M1, M2);
    int q0 = blockIdx.x * 64;
    if (q0 >= Ms) return;

    __shared__ __align__(16) float qs[64][36];
    __shared__ __align__(16) float ks[64][36];
    __shared__ __align__(16) float vs[64][36];
    __shared__ float ps[64][66];
    __shared__ float m_s[64], l_s[64], a_s[64];

    int tid = threadIdx.x;
    const float* base = qkv + (size_t)s * MC * 3 * DD;

    for (int e = tid; e < 64 * 8; e += 256) {
        int r = e >> 3, qq = e & 7;
        int row = q0 + r;
        float4 v4 = make_float4(0.f, 0.f, 0.f, 0.f);
        if (row < Ms) v4 = *(const float4*)(base + (size_t)row * 3 * DD + head * DH + qq * 4);
        *(float4*)&qs[r][qq * 4] = v4;
    }
    if (tid < 64) { m_s[tid] = -1e30f; l_s[tid] = 0.0f; }

    float4 o0 = make_float4(0.f, 0.f, 0.f, 0.f);
    float4 o1 = make_float4(0.f, 0.f, 0.f, 0.f);
    int qi = tid >> 2, sub = tid & 3;
    int nchunks = (Ms + 63) >> 6;
    const float scale = 0.1767766952966369f;  // 1/sqrt(32)

    for (int ch = 0; ch < nchunks; ++ch) {
        int kb = ch * 64;
        __syncthreads();  // protect ks/vs/ps from previous iteration readers
        for (int e = tid; e < 64 * 8; e += 256) {
            int r = e >> 3, qq = e & 7;
            int key = kb + r;
            float4 kv4 = make_float4(0.f, 0.f, 0.f, 0.f);
            float4 vv4 = make_float4(0.f, 0.f, 0.f, 0.f);
            if (key < Ms) {
                kv4 = *(const float4*)(base + (size_t)key * 3 * DD + DD + head * DH + qq * 4);
                vv4 = *(const float4*)(base + (size_t)key * 3 * DD + 2 * DD + head * DH + qq * 4);
            }
            *(float4*)&ks[r][qq * 4] = kv4;
            *(float4*)&vs[r][qq * 4] = vv4;
        }
        __syncthreads();
        {   // scores: 4x4 block per thread
            int qg = (tid & 15) * 4;
            int kg = (tid >> 4) * 4;
            float scr[4][4];
#pragma unroll
            for (int i = 0; i < 4; ++i)
#pragma unroll
                for (int j = 0; j < 4; ++j) scr[i][j] = 0.f;
#pragma unroll
            for (int dq = 0; dq < 8; ++dq) {
                float4 qv[4], kv[4];
#pragma unroll
                for (int i = 0; i < 4; ++i) qv[i] = *(const float4*)&qs[qg + i][dq * 4];
#pragma unroll
                for (int j = 0; j < 4; ++j) kv[j] = *(const float4*)&ks[kg + j][dq * 4];
#pragma unroll
                for (int i = 0; i < 4; ++i)
#pragma unroll
                    for (int j = 0; j < 4; ++j)
                        scr[i][j] += qv[i].x * kv[j].x + qv[i].y * kv[j].y +
                                     qv[i].z * kv[j].z + qv[i].w * kv[j].w;
            }
#pragma unroll
            for (int i = 0; i < 4; ++i)
#pragma unroll
                for (int j = 0; j < 4; ++j) {
                    int kglob = kb + kg + j;
                    ps[qg + i][kg + j] = (kglob < Ms) ? scr[i][j] * scale : -1e30f;
                }
        }
        __syncthreads();
        {   // online softmax update: 4 threads per row
            float mold = m_s[qi];
            float lmax = -1e30f;
            for (int t = 0; t < 16; ++t) lmax = fmaxf(lmax, ps[qi][sub * 16 + t]);
            lmax = fmaxf(lmax, __shfl_xor(lmax, 1));
            lmax = fmaxf(lmax, __shfl_xor(lmax, 2));
            float mnew = fmaxf(mold, lmax);
            float lsum = 0.f;
            for (int t = 0; t < 16; ++t) {
                float e = __expf(ps[qi][sub * 16 + t] - mnew);
                ps[qi][sub * 16 + t] = e;
                lsum += e;
            }
            lsum += __shfl_xor(lsum, 1);
            lsum += __shfl_xor(lsum, 2);
            if (sub == 0) {
                m_s[qi] = mnew;
                float alpha = __expf(mold - mnew);
                l_s[qi] = l_s[qi] * alpha + lsum;
                a_s[qi] = alpha;
            }
        }
        __syncthreads();
        {   // PV accumulate into registers
            float alpha = a_s[qi];
            o0.x *= alpha; o0.y *= alpha; o0.z *= alpha; o0.w *= alpha;
            o1.x *= alpha; o1.y *= alpha; o1.z *= alpha; o1.w *= alpha;
            int d0 = sub * 4, d1 = (sub + 4) * 4;
            for (int key = 0; key < 64; ++key) {
                float p = ps[qi][key];
                float4 va = *(const float4*)&vs[key][d0];
                float4 vb = *(const float4*)&vs[key][d1];
                o0.x += p * va.x; o0.y += p * va.y; o0.z += p * va.z; o0.w += p * va.w;
                o1.x += p * vb.x; o1.y += p * vb.y; o1.z += p * vb.z; o1.w += p * vb.w;
            }
        }
    }
    __syncthreads();
    if (q0 + qi < Ms) {
        float inv = 1.0f / fmaxf(l_s[qi], 1e-30f);
        size_t orow = ((size_t)s * MC + q0 + qi) * DD + head * DH;
        float4 r0 = make_float4(o0.x * inv, o0.y * inv, o0.z * inv, o0.w * inv);
        float4 r1 = make_float4(o1.x * inv, o1.y * inv, o1.z * inv, o1.w * inv);
        *(float4*)(attno + orow + sub * 4) = r0;
        *(float4*)(attno + orow + (sub + 4) * 4) = r1;
    }
}

// ---------------- x1 = LN1(macro + attno @ Wo.T + bo) ----------------
__global__ void k_ln1(const float* __restrict__ macro, const float* __restrict__ attno,
                      const float* __restrict__ Wo, const float* __restrict__ bo,
                      const float* __restrict__ g, const float* __restrict__ b,
                      float* __restrict__ x1,
                      const int* M0, const int* M1, const int* M2)
{
    int s = blockIdx.y;
    int Ms = getM(s, M0, M1, M2);
    int m = blockIdx.x;
    if (m >= Ms) return;
    __shared__ __align__(16) float os[DD];
    __shared__ float red[4];
    int d = threadIdx.x;  // 128
    size_t row = (size_t)s * MC + m;
    os[d] = attno[row * DD + d];
    __syncthreads();
    const float* w = Wo + ((size_t)s * DD + d) * DD;
    float acc = bo[s * DD + d];
    for (int k = 0; k < DD; k += 4) {
        float4 w4 = *(const float4*)(w + k);
        float4 m4 = *(const float4*)&os[k];
        acc += w4.x * m4.x + w4.y * m4.y + w4.z * m4.z + w4.w * m4.w;
    }
    float xin = macro[row * DD + d] + acc;
    float sum = xin, sq = xin * xin;
    for (int off = 32; off >= 1; off >>= 1) { sum += __shfl_xor(sum, off); sq += __shfl_xor(sq, off); }
    if ((d & 63) == 0) { red[d >> 6] = sum; red[2 + (d >> 6)] = sq; }
    __syncthreads();
    sum = red[0] + red[1]; sq = red[2] + red[3];
    float mean = sum * (1.0f / DD);
    float var = fmaxf(sq * (1.0f / DD) - mean * mean, 0.0f);
    float xh = (xin - mean) * rsqrtf(var + 1e-5f);
    x1[row * DD + d] = xh * g[s * DD + d] + b[s * DD + d];
}

// ---------------- x2 = LN2(x1 + relu(x1@W1.T+b1)@W2.T + b2) ----------------
__global__ void k_ffn(const float* __restrict__ x1,
                      const float* __restrict__ W1, const float* __restrict__ b1,
                      const float* __restrict__ W2, const float* __restrict__ b2,
                      const float* __restrict__ g, const float* __restrict__ bb,
                      float* __restrict__ x2,
                      const int* M0, const int* M1, const int* M2)
{
    int s = blockIdx.y;
    int Ms = getM(s, M0, M1, M2);
    int m = blockIdx.x;
    if (m >= Ms) return;
    __shared__ __align__(16) float xr[DD];
    __shared__ __align__(16) float ts[FFD];
    __shared__ float red[8];
    int tid = threadIdx.x;  // 256
    size_t row = (size_t)s * MC + m;
    if (tid < DD) xr[tid] = x1[row * DD + tid];
    __syncthreads();
    {
        const float* w = W1 + ((size_t)s * FFD + tid) * DD;
        float acc = b1[s * FFD + tid];
        for (int k = 0; k < DD; k += 4) {
            float4 w4 = *(const float4*)(w + k);
            float4 m4 = *(const float4*)&xr[k];
            acc += w4.x * m4.x + w4.y * m4.y + w4.z * m4.z + w4.w * m4.w;
        }
        ts[tid] = fmaxf(acc, 0.0f);
    }
    __syncthreads();
    float xin = 0.0f;
    if (tid < DD) {
        const float* w = W2 + ((size_t)s * DD + tid) * FFD;
        float acc = b2[s * DD + tid];
        for (int k = 0; k < FFD; k += 4) {
            float4 w4 = *(const float4*)(w + k);
            float4 m4 = *(const float4*)&ts[k];
            acc += w4.x * m4.x + w4.y * m4.y + w4.z * m4.z + w4.w * m4.w;
        }
        xin = xr[tid] + acc;
    }
    float sum = xin, sq = xin * xin;
    for (int off = 32; off >= 1; off >>= 1) { sum += __shfl_xor(sum, off); sq += __shfl_xor(sq, off); }
    if ((tid & 63) == 0) { red[tid >> 6] = sum; red[4 + (tid >> 6)] = sq; }
    __syncthreads();
    sum = red[0] + red[1] + red[2] + red[3];
    sq = red[4] + red[5] + red[6] + red[7];
    float mean = sum * (1.0f / DD);
    float var = fmaxf(sq * (1.0f / DD) - mean * mean, 0.0f);
    if (tid < DD) {
        float xh = (xin - mean) * rsqrtf(var + 1e-5f);
        x2[row * DD + tid] = xh * g[s * DD + tid] + bb[s * DD + tid];
    }
}

// ---------------- y_s = x2_s @ Wf[:, 128*(s+1):128*(s+2)].T ----------------
__global__ void k_yproj(const float* __restrict__ x2, const float* __restrict__ Wf,
                        float* __restrict__ y,
                        const int* M0, const int* M1, const int* M2)
{
    int s = blockIdx.y;
    int Ms = getM(s, M0, M1, M2);
    int m = blockIdx.x;
    if (m >= Ms) return;
    __shared__ __align__(16) float xr[DD];
    int d = threadIdx.x;  // 128
    size_t row = (size_t)s * MC + m;
    xr[d] = x2[row * DD + d];
    __syncthreads();
    const float* w = Wf + (size_t)d * (4 * DD) + (s + 1) * DD;
    float acc = 0.0f;
    for (int k = 0; k < DD; k += 4) {
        float4 w4 = *(const float4*)(w + k);
        float4 m4 = *(const float4*)&xr[k];
        acc += w4.x * m4.x + w4.y * m4.y + w4.z * m4.z + w4.w * m4.w;
    }
    y[row * DD + d] = acc;
}

// ---------------- out = h@B0 + y0[inv0] + y1[inv1] + y2[inv2] + bf ----------------
__global__ __launch_bounds__(256) void k_final(const float* __restrict__ h,
                                               const float* __restrict__ B0T,
                                               const float* __restrict__ y,
                                               const int* __restrict__ inv0,
                                               const int* __restrict__ inv1,
                                               const int* __restrict__ inv2,
                                               const float* __restrict__ bf,
                                               float* __restrict__ out, int N)
{
    __shared__ __align__(16) float hs[64][132];
    int tid = threadIdx.x;
    int ntiles = (N + 63) >> 6;
    const float* y0 = y;
    const float* y1 = y + (size_t)MC * DD;
    const float* y2 = y + (size_t)2 * MC * DD;
    for (int t = blockIdx.x; t < ntiles; t += gridDim.x) {
        int pb = t * 64;
        __syncthreads();
        for (int fq = tid; fq < 64 * 32; fq += 256) {
            int p = fq >> 5, q = fq & 31;
            float4 v4 = make_float4(0.f, 0.f, 0.f, 0.f);
            if (pb + p < N) v4 = *(const float4*)(h + ((size_t)(pb + p)) * DD + q * 4);
            *(float4*)&hs[p][q * 4] = v4;
        }
        __syncthreads();
        int pg = tid & 15, dg = tid >> 4;
        int d0 = dg * 8;
        float4 a0[4], a1[4];
#pragma unroll
        for (int i = 0; i < 4; ++i) {
            a0[i] = make_float4(0.f, 0.f, 0.f, 0.f);
            a1[i] = make_float4(0.f, 0.f, 0.f, 0.f);
        }
        for (int k = 0; k < DD; k += 4) {
            float4 h4[4];
#pragma unroll
            for (int i = 0; i < 4; ++i) h4[i] = *(const float4*)&hs[pg + 16 * i][k];
#pragma unroll
            for (int kk = 0; kk < 4; ++kk) {
                float4 ba = *(const float4*)(B0T + (size_t)(k + kk) * DD + d0);
                float4 bb = *(const float4*)(B0T + (size_t)(k + kk) * DD + d0 + 4);
#pragma unroll
                for (int i = 0; i < 4; ++i) {
                    float hv = (kk == 0) ? h4[i].x : (kk == 1) ? h4[i].y : (kk == 2) ? h4[i].z : h4[i].w;
                    a0[i].x += hv * ba.x; a0[i].y += hv * ba.y; a0[i].z += hv * ba.z; a0[i].w += hv * ba.w;
                    a1[i].x += hv * bb.x; a1[i].y += hv * bb.y; a1[i].z += hv * bb.z; a1[i].w += hv * bb.w;
                }
            }
        }
        float4 bf0 = *(const float4*)(bf + d0);
        float4 bf1 = *(const float4*)(bf + d0 + 4);
#pragma unroll
        for (int i = 0; i < 4; ++i) {
            int p = pb + pg + 16 * i;
            if (p >= N) continue;
            int i0 = inv0[p], i1 = inv1[p], i2 = inv2[p];
            float4 g0 = *(const float4*)(y0 + (size_t)i0 * DD + d0);
            float4 g0b = *(const float4*)(y0 + (size_t)i0 * DD + d0 + 4);
            float4 g1 = *(const float4*)(y1 + (size_t)i1 * DD + d0);
            float4 g1b = *(const float4*)(y1 + (size_t)i1 * DD + d0 + 4);
            float4 g2 = *(const float4*)(y2 + (size_t)i2 * DD + d0);
            float4 g2b = *(const float4*)(y2 + (size_t)i2 * DD + d0 + 4);
            float4 r0 = make_float4(a0[i].x + g0.x + g1.x + g2.x + bf0.x,
                                    a0[i].y + g0.y + g1.y + g2.y + bf0.y,
                                    a0[i].z + g0.z + g1.z + g2.z + bf0.z,
                                    a0[i].w + g0.w + g1.w + g2.w + bf0.w);
            float4 r1 = make_float4(a1[i].x + g0b.x + g1b.x + g2b.x + bf1.x,
                                    a1[i].y + g0b.y + g1b.y + g2b.y + bf1.y,
                                    a1[i].z + g0b.z + g1b.z + g2b.z + bf1.z,
                                    a1[i].w + g0b.w + g1b.w + g2b.w + bf1.w);
            *(float4*)(out + (size_t)p * DD + d0) = r0;
            *(float4*)(out + (size_t)p * DD + d0 + 4) = r1;
        }
    }
}

extern "C" void kernel_launch(void* const* d_in, const int* in_sizes, int n_in,
                              void* d_out, int out_size, void* d_ws, size_t ws_size,
                              hipStream_t stream) {
    (void)n_in; (void)out_size; (void)ws_size;
    const float* h   = (const float*)d_in[0];
    const int* inv0  = (const int*)d_in[2];
    const int* inv1  = (const int*)d_in[3];
    const int* inv2  = (const int*)d_in[4];
    const int* M0    = (const int*)d_in[5];
    const int* M1    = (const int*)d_in[6];
    const int* M2    = (const int*)d_in[7];
    const float* Wqkv = (const float*)d_in[8];
    const float* bqkv = (const float*)d_in[9];
    const float* Wo   = (const float*)d_in[10];
    const float* bo   = (const float*)d_in[11];
    const float* ln1s = (const float*)d_in[12];
    const float* ln1b = (const float*)d_in[13];
    const float* W1   = (const float*)d_in[14];
    const float* b1   = (const float*)d_in[15];
    const float* W2   = (const float*)d_in[16];
    const float* b2   = (const float*)d_in[17];
    const float* ln2s = (const float*)d_in[18];
    const float* ln2b = (const float*)d_in[19];
    const float* Wf   = (const float*)d_in[20];
    const float* bf   = (const float*)d_in[21];
    int N = in_sizes[0] / DD;

    float* ws     = (float*)d_ws;
    float* macro  = ws;                                     // NS*MC*DD (sums, then means)
    float* counts = macro + (size_t)NS * MC * DD;           // NS*MC
    float* qkvb   = counts + (size_t)NS * MC;               // NS*MC*3*DD
    float* attno  = qkvb + (size_t)NS * MC * 3 * DD;        // NS*MC*DD
    float* x1     = attno + (size_t)NS * MC * DD;           // NS*MC*DD
    float* x2     = x1 + (size_t)NS * MC * DD;              // NS*MC*DD
    float* yb     = x2 + (size_t)NS * MC * DD;              // NS*MC*DD
    float* B0T    = yb + (size_t)NS * MC * DD;              // DD*DD
    int*   parent10 = (int*)(B0T + (size_t)DD * DD);        // MC
    int*   parent21 = parent10 + MC;                        // 512

    float* sum0 = macro;
    float* sum1 = macro + (size_t)1 * MC * DD;
    float* sum2 = macro + (size_t)2 * MC * DD;
    float* cnt0 = counts;
    float* cnt1 = counts + MC;
    float* cnt2 = counts + 2 * MC;

    hipMemsetAsync(macro, 0, ((size_t)NS * MC * DD + NS * MC) * sizeof(float), stream);

    k_parent<<<(N + 255) / 256, 256, 0, stream>>>(inv0, inv1, inv2, parent10, parent21, N);

    long long total = (long long)N * DD;
    int sblocks = (int)((total + 255) / 256);
    k_scatter0<<<sblocks, 256, 0, stream>>>(h, inv0, sum0, cnt0, N);
    k_rollup<<<(MC * DD) / 256, 256, 0, stream>>>(sum0, cnt0, parent10, sum1, cnt1, M0, MC);
    k_rollup<<<(512 * DD) / 256, 256, 0, stream>>>(sum1, cnt1, parent21, sum2, cnt2, M1, 512);
    k_finalize<<<(NS * MC * DD) / 256, 256, 0, stream>>>(macro, counts, M0, M1, M2);
    k_b0t<<<64, 256, 0, stream>>>(Wf, B0T);
    k_qkv<<<dim3(MC / 8, NS), 256, 0, stream>>>(macro, Wqkv, bqkv, qkvb, M0, M1, M2);
    k_attn<<<dim3(MC / 64, NHH, NS), 256, 0, stream>>>(qkvb, attno, M0, M1, M2);
    k_ln1<<<dim3(MC, NS), 128, 0, stream>>>(macro, attno, Wo, bo, ln1s, ln1b, x1, M0, M1, M2);
    k_ffn<<<dim3(MC, NS), 256, 0, stream>>>(x1, W1, b1, W2, b2, ln2s, ln2b, x2, M0, M1, M2);
    k_yproj<<<dim3(MC, NS), 128, 0, stream>>>(x2, Wf, yb, M0, M1, M2);
    k_final<<<2048, 256, 0, stream>>>(h, B0T, yb, inv0, inv1, inv2, bf, (float*)d_out, N);
}

// Round 3
// 1282.169 us; speedup vs baseline: 3.6888x; 1.0246x over previous
//
#include <hip/hip_runtime.h>
#include <hip/hip_bf16.h>

#define MC 4096
#define DD 128
#define NHH 4
#define DH 32
#define FFD 256
#define NS 3
#define NSPLIT 4
#define PLEN 1024

__device__ __forceinline__ int getM(int s, const int* M0, const int* M1, const int* M2) {
    return (s == 0) ? *M0 : (s == 1) ? *M1 : *M2;
}

// ---------------- parent maps from inv arrays (nested grids) ----------------
__global__ void k_parent(const int* __restrict__ inv0, const int* __restrict__ inv1,
                         const int* __restrict__ inv2,
                         int* __restrict__ parent10, int* __restrict__ parent21, int N)
{
    int n = blockIdx.x * blockDim.x + threadIdx.x;
    if (n >= N) return;
    parent10[inv0[n]] = inv1[n];   // duplicate writes all agree (grids nest)
    parent21[inv1[n]] = inv2[n];
}

// ---------------- counting sort: histogram ----------------
__global__ void k_hist(const int* __restrict__ inv0, int* __restrict__ cnt, int N)
{
    int n = blockIdx.x * blockDim.x + threadIdx.x;
    if (n < N) atomicAdd(&cnt[inv0[n]], 1);
}

// ---------------- exclusive scan over MC=4096 bins, single block 1024 thr ----------------
__global__ void k_scan(const int* __restrict__ cnt, int* __restrict__ offs)
{
    __shared__ int arr[1024];
    int tid = threadIdx.x;
    int base = tid * 4;
    int c0 = cnt[base], c1 = cnt[base + 1], c2 = cnt[base + 2], c3 = cnt[base + 3];
    int tot = c0 + c1 + c2 + c3;
    arr[tid] = tot;
    __syncthreads();
    for (int off = 1; off < 1024; off <<= 1) {
        int v = (tid >= off) ? arr[tid - off] : 0;
        __syncthreads();
        arr[tid] += v;
        __syncthreads();
    }
    int excl = arr[tid] - tot;
    offs[base] = excl;
    offs[base + 1] = excl + c0;
    offs[base + 2] = excl + c0 + c1;
    offs[base + 3] = excl + c0 + c1 + c2;
}

// ---------------- placement: order[] groups particles by voxel ----------------
__global__ void k_place(const int* __restrict__ inv0, const int* __restrict__ offs,
                        int* __restrict__ fill, int* __restrict__ order, int N)
{
    int n = blockIdx.x * blockDim.x + threadIdx.x;
    if (n >= N) return;
    int i0 = inv0[n];
    int pos = offs[i0] + atomicAdd(&fill[i0], 1);
    order[pos] = n;
}

// ---------------- pooled sums, no fp atomics: one block per voxel ----------------
__global__ __launch_bounds__(256) void k_pool(const float* __restrict__ h,
                                              const int* __restrict__ order,
                                              const int* __restrict__ offs,
                                              const int* __restrict__ cnt,
                                              float* __restrict__ sum0, float* __restrict__ cnt0,
                                              const int* __restrict__ M0)
{
    int v = blockIdx.x;
    if (v >= *M0) return;
    int beg = offs[v], len = cnt[v];
    int tid = threadIdx.x;
    int d = tid & 127, half = tid >> 7;
    float acc = 0.f;
    for (int j = half; j < len; j += 2) {
        int row = order[beg + j];
        acc += h[(size_t)row * DD + d];
    }
    __shared__ float red[DD];
    if (half == 1) red[d] = acc;
    __syncthreads();
    if (half == 0) {
        acc += red[d];
        sum0[(size_t)v * DD + d] = acc;
        if (d == 0) cnt0[v] = (float)len;
    }
}

// ---------------- roll coarse sums up the hierarchy ----------------
__global__ void k_rollup(const float* __restrict__ sumSrc, const float* __restrict__ cntSrc,
                         const int* __restrict__ parent,
                         float* __restrict__ sumDst, float* __restrict__ cntDst,
                         const int* __restrict__ Msrc, int cap)
{
    int idx = blockIdx.x * blockDim.x + threadIdx.x;   // < cap*DD
    int v = idx >> 7, d = idx & 127;
    int Ms = *Msrc;
    if (Ms > cap) Ms = cap;
    if (v >= Ms) return;
    int p = parent[v];
    atomicAdd(&sumDst[(size_t)p * DD + d], sumSrc[idx]);
    if (d == 0) atomicAdd(&cntDst[p], cntSrc[v]);
}

// ---------------- divide by clamped counts ----------------
__global__ void k_finalize(float* __restrict__ macro, const float* __restrict__ counts,
                           const int* M0, const int* M1, const int* M2)
{
    int idx = blockIdx.x * blockDim.x + threadIdx.x;  // < NS*MC*DD
    int s = idx / (MC * DD);
    int r = (idx >> 7) & (MC - 1);
    if (r >= getM(s, M0, M1, M2)) return;
    float c = counts[s * MC + r];
    macro[idx] /= fmaxf(c, 1.0f);
}

// ---------------- B0T[k][d] = Wf[d][k] ----------------
__global__ void k_b0t(const float* __restrict__ Wf, float* __restrict__ B0T)
{
    int idx = blockIdx.x * 256 + threadIdx.x;  // 16384
    int k = idx >> 7, d = idx & 127;
    B0T[idx] = Wf[(size_t)d * (4 * DD) + k];
}

// ---------------- qkv = macro @ Wqkv[s].T + bqkv[s], 8 rows/block ----------------
__global__ void k_qkv(const float* __restrict__ macro, const float* __restrict__ Wqkv,
                      const float* __restrict__ bqkv, float* __restrict__ qkv,
                      const int* M0, const int* M1, const int* M2)
{
    int s = blockIdx.y;
    int Ms = getM(s, M0, M1, M2);
    int row0 = blockIdx.x * 8;
    if (row0 >= Ms) return;
    __shared__ __align__(16) float mac[8][DD];
    int tid = threadIdx.x;
    for (int e = tid; e < 8 * DD; e += 256) {
        int r = e >> 7, d = e & 127;
        int row = row0 + r;
        mac[r][d] = (row < Ms) ? macro[(size_t)s * MC * DD + (size_t)row * DD + d] : 0.0f;
    }
    __syncthreads();
    for (int j = tid; j < 3 * DD; j += 256) {
        const float* w = Wqkv + ((size_t)s * 3 * DD + j) * DD;
        float b = bqkv[s * 3 * DD + j];
        float acc[8];
#pragma unroll
        for (int r = 0; r < 8; ++r) acc[r] = b;
        for (int k = 0; k < DD; k += 4) {
            float4 w4 = *(const float4*)(w + k);
#pragma unroll
            for (int r = 0; r < 8; ++r) {
                float4 m4 = *(const float4*)&mac[r][k];
                acc[r] += w4.x * m4.x + w4.y * m4.y + w4.z * m4.z + w4.w * m4.w;
            }
        }
        for (int r = 0; r < 8; ++r) {
            int row = row0 + r;
            if (row < Ms) qkv[((size_t)s * MC + row) * (3 * DD) + j] = acc[r];
        }
    }
}

// ---------------- flash attention partials: split-K over NSPLIT partitions ----------------
__global__ __launch_bounds__(256) void k_attn_part(const float* __restrict__ qkv,
                                                   float* __restrict__ part_o,
                                                   float* __restrict__ part_ml,
                                                   const int* M0, const int* M1, const int* M2)
{
    int z = blockIdx.z;
    int s = z / NSPLIT, part = z % NSPLIT;
    int head = blockIdx.y;
    int Ms = getM(s, M0, M1, M2);
    int q0 = blockIdx.x * 64;
    if (q0 >= Ms) return;
    int kstart = part * PLEN;
    if (kstart >= Ms) return;
    int kend = kstart + PLEN; if (kend > Ms) kend = Ms;

    __shared__ __align__(16) float qs[64][36];
    __shared__ __align__(16) float ks[64][36];
    __shared__ __align__(16) float vs[64][36];
    __shared__ float ps[64][66];
    __shared__ float m_s[64], l_s[64], a_s[64];

    int tid = threadIdx.x;
    const float* base = qkv + (size_t)s * MC * 3 * DD;

    for (int e = tid; e < 64 * 8; e += 256) {
        int r = e >> 3, qq = e & 7;
        int row = q0 + r;
        float4 v4 = make_float4(0.f, 0.f, 0.f, 0.f);
        if (row < Ms) v4 = *(const float4*)(base + (size_t)row * 3 * DD + head * DH + qq * 4);
        *(float4*)&qs[r][qq * 4] = v4;
    }
    if (tid < 64) { m_s[tid] = -1e30f; l_s[tid] = 0.0f; }

    float4 o0 = make_float4(0.f, 0.f, 0.f, 0.f);
    float4 o1 = make_float4(0.f, 0.f, 0.f, 0.f);
    int qi = tid >> 2, sub = tid & 3;
    const float scale = 0.1767766952966369f;  // 1/sqrt(32)

    int c0 = kstart >> 6, c1 = (kend + 63) >> 6;
    for (int ch = c0; ch < c1; ++ch) {
        int kb = ch * 64;
        __syncthreads();
        for (int e = tid; e < 64 * 8; e += 256) {
            int r = e >> 3, qq = e & 7;
            int key = kb + r;
            float4 kv4 = make_float4(0.f, 0.f, 0.f, 0.f);
            float4 vv4 = make_float4(0.f, 0.f, 0.f, 0.f);
            if (key < kend) {
                kv4 = *(const float4*)(base + (size_t)key * 3 * DD + DD + head * DH + qq * 4);
                vv4 = *(const float4*)(base + (size_t)key * 3 * DD + 2 * DD + head * DH + qq * 4);
            }
            *(float4*)&ks[r][qq * 4] = kv4;
            *(float4*)&vs[r][qq * 4] = vv4;
        }
        __syncthreads();
        {   // scores: 4x4 block per thread
            int qg = (tid & 15) * 4;
            int kg = (tid >> 4) * 4;
            float scr[4][4];
#pragma unroll
            for (int i = 0; i < 4; ++i)
#pragma unroll
                for (int j = 0; j < 4; ++j) scr[i][j] = 0.f;
#pragma unroll
            for (int dq = 0; dq < 8; ++dq) {
                float4 qv[4], kv[4];
#pragma unroll
                for (int i = 0; i < 4; ++i) qv[i] = *(const float4*)&qs[qg + i][dq * 4];
#pragma unroll
                for (int j = 0; j < 4; ++j) kv[j] = *(const float4*)&ks[kg + j][dq * 4];
#pragma unroll
                for (int i = 0; i < 4; ++i)
#pragma unroll
                    for (int j = 0; j < 4; ++j)
                        scr[i][j] += qv[i].x * kv[j].x + qv[i].y * kv[j].y +
                                     qv[i].z * kv[j].z + qv[i].w * kv[j].w;
            }
#pragma unroll
            for (int i = 0; i < 4; ++i)
#pragma unroll
                for (int j = 0; j < 4; ++j) {
                    int kglob = kb + kg + j;
                    ps[qg + i][kg + j] = (kglob < kend) ? scr[i][j] * scale : -1e30f;
                }
        }
        __syncthreads();
        {   // online softmax update: 4 threads per row
            float mold = m_s[qi];
            float lmax = -1e30f;
            for (int t = 0; t < 16; ++t) lmax = fmaxf(lmax, ps[qi][sub * 16 + t]);
            lmax = fmaxf(lmax, __shfl_xor(lmax, 1));
            lmax = fmaxf(lmax, __shfl_xor(lmax, 2));
            float mnew = fmaxf(mold, lmax);
            float lsum = 0.f;
            for (int t = 0; t < 16; ++t) {
                float e = __expf(ps[qi][sub * 16 + t] - mnew);
                ps[qi][sub * 16 + t] = e;
                lsum += e;
            }
            lsum += __shfl_xor(lsum, 1);
            lsum += __shfl_xor(lsum, 2);
            if (sub == 0) {
                m_s[qi] = mnew;
                float alpha = __expf(mold - mnew);
                l_s[qi] = l_s[qi] * alpha + lsum;
                a_s[qi] = alpha;
            }
        }
        __syncthreads();
        {   // PV accumulate into registers (unnormalized)
            float alpha = a_s[qi];
            o0.x *= alpha; o0.y *= alpha; o0.z *= alpha; o0.w *= alpha;
            o1.x *= alpha; o1.y *= alpha; o1.z *= alpha; o1.w *= alpha;
            int d0 = sub * 4, d1 = (sub + 4) * 4;
            for (int key = 0; key < 64; ++key) {
                float p = ps[qi][key];
                float4 va = *(const float4*)&vs[key][d0];
                float4 vb = *(const float4*)&vs[key][d1];
                o0.x += p * va.x; o0.y += p * va.y; o0.z += p * va.z; o0.w += p * va.w;
                o1.x += p * vb.x; o1.y += p * vb.y; o1.z += p * vb.z; o1.w += p * vb.w;
            }
        }
    }
    __syncthreads();
    int rec = ((s * NHH + head) * 64 + blockIdx.x) * NSPLIT + part;
    float* po = part_o + (size_t)rec * 2048;
    *(float4*)(po + qi * 32 + sub * 4) = o0;
    *(float4*)(po + qi * 32 + (sub + 4) * 4) = o1;
    if (sub == 0) {
        part_ml[rec * 128 + qi] = m_s[qi];
        part_ml[rec * 128 + 64 + qi] = l_s[qi];
    }
}

// ---------------- merge split-K partials ----------------
__global__ void k_attn_comb(const float* __restrict__ part_o, const float* __restrict__ part_ml,
                            float* __restrict__ attno,
                            const int* M0, const int* M1, const int* M2)
{
    int s = blockIdx.z, head = blockIdx.y;
    int Ms = getM(s, M0, M1, M2);
    int q0 = blockIdx.x * 64;
    if (q0 >= Ms) return;
    int tid = threadIdx.x;
    int qi = tid >> 2, sub = tid & 3;
    int nparts = (Ms + PLEN - 1) / PLEN;
    if (nparts > NSPLIT) nparts = NSPLIT;
    int recbase = ((s * NHH + head) * 64 + blockIdx.x) * NSPLIT;

    float m = -1e30f;
    for (int p = 0; p < nparts; ++p)
        m = fmaxf(m, part_ml[(recbase + p) * 128 + qi]);
    float L = 0.f;
    float4 O0 = make_float4(0.f, 0.f, 0.f, 0.f);
    float4 O1 = make_float4(0.f, 0.f, 0.f, 0.f);
    for (int p = 0; p < nparts; ++p) {
        float mp = part_ml[(recbase + p) * 128 + qi];
        float lp = part_ml[(recbase + p) * 128 + 64 + qi];
        float w = __expf(mp - m);
        L += lp * w;
        const float* po = part_o + (size_t)(recbase + p) * 2048;
        float4 a = *(const float4*)(po + qi * 32 + sub * 4);
        float4 b = *(const float4*)(po + qi * 32 + (sub + 4) * 4);
        O0.x += a.x * w; O0.y += a.y * w; O0.z += a.z * w; O0.w += a.w * w;
        O1.x += b.x * w; O1.y += b.y * w; O1.z += b.z * w; O1.w += b.w * w;
    }
    if (q0 + qi < Ms) {
        float inv = 1.0f / fmaxf(L, 1e-30f);
        size_t orow = ((size_t)s * MC + q0 + qi) * DD + head * DH;
        float4 r0 = make_float4(O0.x * inv, O0.y * inv, O0.z * inv, O0.w * inv);
        float4 r1 = make_float4(O1.x * inv, O1.y * inv, O1.z * inv, O1.w * inv);
        *(float4*)(attno + orow + sub * 4) = r0;
        *(float4*)(attno + orow + (sub + 4) * 4) = r1;
    }
}

// ---------------- x1 = LN1(macro + attno @ Wo.T + bo) ----------------
__global__ void k_ln1(const float* __restrict__ macro, const float* __restrict__ attno,
                      const float* __restrict__ Wo, const float* __restrict__ bo,
                      const float* __restrict__ g, const float* __restrict__ b,
                      float* __restrict__ x1,
                      const int* M0, const int* M1, const int* M2)
{
    int s = blockIdx.y;
    int Ms = getM(s, M0, M1, M2);
    int m = blockIdx.x;
    if (m >= Ms) return;
    __shared__ __align__(16) float os[DD];
    __shared__ float red[4];
    int d = threadIdx.x;  // 128
    size_t row = (size_t)s * MC + m;
    os[d] = attno[row * DD + d];
    __syncthreads();
    const float* w = Wo + ((size_t)s * DD + d) * DD;
    float acc = bo[s * DD + d];
    for (int k = 0; k < DD; k += 4) {
        float4 w4 = *(const float4*)(w + k);
        float4 m4 = *(const float4*)&os[k];
        acc += w4.x * m4.x + w4.y * m4.y + w4.z * m4.z + w4.w * m4.w;
    }
    float xin = macro[row * DD + d] + acc;
    float sum = xin, sq = xin * xin;
    for (int off = 32; off >= 1; off >>= 1) { sum += __shfl_xor(sum, off); sq += __shfl_xor(sq, off); }
    if ((d & 63) == 0) { red[d >> 6] = sum; red[2 + (d >> 6)] = sq; }
    __syncthreads();
    sum = red[0] + red[1]; sq = red[2] + red[3];
    float mean = sum * (1.0f / DD);
    float var = fmaxf(sq * (1.0f / DD) - mean * mean, 0.0f);
    float xh = (xin - mean) * rsqrtf(var + 1e-5f);
    x1[row * DD + d] = xh * g[s * DD + d] + b[s * DD + d];
}

// ---------------- x2 = LN2(x1 + relu(x1@W1.T+b1)@W2.T + b2) ----------------
__global__ void k_ffn(const float* __restrict__ x1,
                      const float* __restrict__ W1, const float* __restrict__ b1,
                      const float* __restrict__ W2, const float* __restrict__ b2,
                      const float* __restrict__ g, const float* __restrict__ bb,
                      float* __restrict__ x2,
                      const int* M0, const int* M1, const int* M2)
{
    int s = blockIdx.y;
    int Ms = getM(s, M0, M1, M2);
    int m = blockIdx.x;
    if (m >= Ms) return;
    __shared__ __align__(16) float xr[DD];
    __shared__ __align__(16) float ts[FFD];
    __shared__ float red[8];
    int tid = threadIdx.x;  // 256
    size_t row = (size_t)s * MC + m;
    if (tid < DD) xr[tid] = x1[row * DD + tid];
    __syncthreads();
    {
        const float* w = W1 + ((size_t)s * FFD + tid) * DD;
        float acc = b1[s * FFD + tid];
        for (int k = 0; k < DD; k += 4) {
            float4 w4 = *(const float4*)(w + k);
            float4 m4 = *(const float4*)&xr[k];
            acc += w4.x * m4.x + w4.y * m4.y + w4.z * m4.z + w4.w * m4.w;
        }
        ts[tid] = fmaxf(acc, 0.0f);
    }
    __syncthreads();
    float xin = 0.0f;
    if (tid < DD) {
        const float* w = W2 + ((size_t)s * DD + tid) * FFD;
        float acc = b2[s * DD + tid];
        for (int k = 0; k < FFD; k += 4) {
            float4 w4 = *(const float4*)(w + k);
            float4 m4 = *(const float4*)&ts[k];
            acc += w4.x * m4.x + w4.y * m4.y + w4.z * m4.z + w4.w * m4.w;
        }
        xin = xr[tid] + acc;
    }
    float sum = xin, sq = xin * xin;
    for (int off = 32; off >= 1; off >>= 1) { sum += __shfl_xor(sum, off); sq += __shfl_xor(sq, off); }
    if ((tid & 63) == 0) { red[tid >> 6] = sum; red[4 + (tid >> 6)] = sq; }
    __syncthreads();
    sum = red[0] + red[1] + red[2] + red[3];
    sq = red[4] + red[5] + red[6] + red[7];
    float mean = sum * (1.0f / DD);
    float var = fmaxf(sq * (1.0f / DD) - mean * mean, 0.0f);
    if (tid < DD) {
        float xh = (xin - mean) * rsqrtf(var + 1e-5f);
        x2[row * DD + tid] = xh * g[s * DD + tid] + bb[s * DD + tid];
    }
}

// ---------------- y_s = x2_s @ Wf[:, 128*(s+1):128*(s+2)].T ----------------
__global__ void k_yproj(const float* __restrict__ x2, const float* __restrict__ Wf,
                        float* __restrict__ y,
                        const int* M0, const int* M1, const int* M2)
{
    int s = blockIdx.y;
    int Ms = getM(s, M0, M1, M2);
    int m = blockIdx.x;
    if (m >= Ms) return;
    __shared__ __align__(16) float xr[DD];
    int d = threadIdx.x;  // 128
    size_t row = (size_t)s * MC + m;
    xr[d] = x2[row * DD + d];
    __syncthreads();
    const float* w = Wf + (size_t)d * (4 * DD) + (s + 1) * DD;
    float acc = 0.0f;
    for (int k = 0; k < DD; k += 4) {
        float4 w4 = *(const float4*)(w + k);
        float4 m4 = *(const float4*)&xr[k];
        acc += w4.x * m4.x + w4.y * m4.y + w4.z * m4.z + w4.w * m4.w;
    }
    y[row * DD + d] = acc;
}

// ---------------- out = h@B0 + y0[inv0] + y1[inv1] + y2[inv2] + bf ----------------
__global__ __launch_bounds__(256) void k_final(const float* __restrict__ h,
                                               const float* __restrict__ B0T,
                                               const float* __restrict__ y,
                                               const int* __restrict__ inv0,
                                               const int* __restrict__ inv1,
                                               const int* __restrict__ inv2,
                                               const float* __restrict__ bf,
                                               float* __restrict__ out, int N)
{
    __shared__ __align__(16) float hs[64][132];
    int tid = threadIdx.x;
    int ntiles = (N + 63) >> 6;
    const float* y0 = y;
    const float* y1 = y + (size_t)MC * DD;
    const float* y2 = y + (size_t)2 * MC * DD;
    for (int t = blockIdx.x; t < ntiles; t += gridDim.x) {
        int pb = t * 64;
        __syncthreads();
        for (int fq = tid; fq < 64 * 32; fq += 256) {
            int p = fq >> 5, q = fq & 31;
            float4 v4 = make_float4(0.f, 0.f, 0.f, 0.f);
            if (pb + p < N) v4 = *(const float4*)(h + ((size_t)(pb + p)) * DD + q * 4);
            *(float4*)&hs[p][q * 4] = v4;
        }
        __syncthreads();
        int pg = tid & 15, dg = tid >> 4;
        int d0 = dg * 8;
        float4 a0[4], a1[4];
#pragma unroll
        for (int i = 0; i < 4; ++i) {
            a0[i] = make_float4(0.f, 0.f, 0.f, 0.f);
            a1[i] = make_float4(0.f, 0.f, 0.f, 0.f);
        }
        for (int k = 0; k < DD; k += 4) {
            float4 h4[4];
#pragma unroll
            for (int i = 0; i < 4; ++i) h4[i] = *(const float4*)&hs[pg + 16 * i][k];
#pragma unroll
            for (int kk = 0; kk < 4; ++kk) {
                float4 ba = *(const float4*)(B0T + (size_t)(k + kk) * DD + d0);
                float4 bb = *(const float4*)(B0T + (size_t)(k + kk) * DD + d0 + 4);
#pragma unroll
                for (int i = 0; i < 4; ++i) {
                    float hv = (kk == 0) ? h4[i].x : (kk == 1) ? h4[i].y : (kk == 2) ? h4[i].z : h4[i].w;
                    a0[i].x += hv * ba.x; a0[i].y += hv * ba.y; a0[i].z += hv * ba.z; a0[i].w += hv * ba.w;
                    a1[i].x += hv * bb.x; a1[i].y += hv * bb.y; a1[i].z += hv * bb.z; a1[i].w += hv * bb.w;
                }
            }
        }
        float4 bf0 = *(const float4*)(bf + d0);
        float4 bf1 = *(const float4*)(bf + d0 + 4);
#pragma unroll
        for (int i = 0; i < 4; ++i) {
            int p = pb + pg + 16 * i;
            if (p >= N) continue;
            int i0 = inv0[p], i1 = inv1[p], i2 = inv2[p];
            float4 g0 = *(const float4*)(y0 + (size_t)i0 * DD + d0);
            float4 g0b = *(const float4*)(y0 + (size_t)i0 * DD + d0 + 4);
            float4 g1 = *(const float4*)(y1 + (size_t)i1 * DD + d0);
            float4 g1b = *(const float4*)(y1 + (size_t)i1 * DD + d0 + 4);
            float4 g2 = *(const float4*)(y2 + (size_t)i2 * DD + d0);
            float4 g2b = *(const float4*)(y2 + (size_t)i2 * DD + d0 + 4);
            float4 r0 = make_float4(a0[i].x + g0.x + g1.x + g2.x + bf0.x,
                                    a0[i].y + g0.y + g1.y + g2.y + bf0.y,
                                    a0[i].z + g0.z + g1.z + g2.z + bf0.z,
                                    a0[i].w + g0.w + g1.w + g2.w + bf0.w);
            float4 r1 = make_float4(a1[i].x + g0b.x + g1b.x + g2b.x + bf1.x,
                                    a1[i].y + g0b.y + g1b.y + g2b.y + bf1.y,
                                    a1[i].z + g0b.z + g1b.z + g2b.z + bf1.z,
                                    a1[i].w + g0b.w + g1b.w + g2b.w + bf1.w);
            *(float4*)(out + (size_t)p * DD + d0) = r0;
            *(float4*)(out + (size_t)p * DD + d0 + 4) = r1;
        }
    }
}

extern "C" void kernel_launch(void* const* d_in, const int* in_sizes, int n_in,
                              void* d_out, int out_size, void* d_ws, size_t ws_size,
                              hipStream_t stream) {
    (void)n_in; (void)out_size; (void)ws_size;
    const float* h   = (const float*)d_in[0];
    const int* inv0  = (const int*)d_in[2];
    const int* inv1  = (const int*)d_in[3];
    const int* inv2  = (const int*)d_in[4];
    const int* M0    = (const int*)d_in[5];
    const int* M1    = (const int*)d_in[6];
    const int* M2    = (const int*)d_in[7];
    const float* Wqkv = (const float*)d_in[8];
    const float* bqkv = (const float*)d_in[9];
    const float* Wo   = (const float*)d_in[10];
    const float* bo   = (const float*)d_in[11];
    const float* ln1s = (const float*)d_in[12];
    const float* ln1b = (const float*)d_in[13];
    const float* W1   = (const float*)d_in[14];
    const float* b1   = (const float*)d_in[15];
    const float* W2   = (const float*)d_in[16];
    const float* b2   = (const float*)d_in[17];
    const float* ln2s = (const float*)d_in[18];
    const float* ln2b = (const float*)d_in[19];
    const float* Wf   = (const float*)d_in[20];
    const float* bf   = (const float*)d_in[21];
    int N = in_sizes[0] / DD;

    float* ws      = (float*)d_ws;
    float* macro   = ws;                                    // NS*MC*DD
    float* counts  = macro + (size_t)NS * MC * DD;          // NS*MC
    float* qkvb    = counts + (size_t)NS * MC;              // NS*MC*3*DD
    float* attno   = qkvb + (size_t)NS * MC * 3 * DD;       // NS*MC*DD
    float* x1      = attno + (size_t)NS * MC * DD;          // NS*MC*DD
    float* x2      = x1 + (size_t)NS * MC * DD;             // NS*MC*DD
    float* yb      = x2 + (size_t)NS * MC * DD;             // NS*MC*DD
    float* B0T     = yb + (size_t)NS * MC * DD;             // DD*DD
    float* part_o  = B0T + (size_t)DD * DD;                 // NS*NHH*64*NSPLIT*2048
    float* part_ml = part_o + (size_t)NS * NHH * 64 * NSPLIT * 2048;  // NS*NHH*64*NSPLIT*128
    int* ip        = (int*)(part_ml + (size_t)NS * NHH * 64 * NSPLIT * 128);
    int* parent10  = ip;                // MC
    int* parent21  = parent10 + MC;     // 512
    int* cnt_i     = parent21 + 512;    // MC
    int* fill      = cnt_i + MC;        // MC
    int* offs      = fill + MC;         // MC
    int* order     = offs + MC;         // N

    float* sum0 = macro;
    float* sum1 = macro + (size_t)1 * MC * DD;
    float* sum2 = macro + (size_t)2 * MC * DD;
    float* cnt0 = counts;
    float* cnt1 = counts + MC;
    float* cnt2 = counts + 2 * MC;

    hipMemsetAsync(macro, 0, ((size_t)NS * MC * DD + NS * MC) * sizeof(float), stream);
    hipMemsetAsync(cnt_i, 0, (size_t)2 * MC * sizeof(int), stream);

    int nb = (N + 255) / 256;
    k_parent<<<nb, 256, 0, stream>>>(inv0, inv1, inv2, parent10, parent21, N);
    k_hist<<<nb, 256, 0, stream>>>(inv0, cnt_i, N);
    k_scan<<<1, 1024, 0, stream>>>(cnt_i, offs);
    k_place<<<nb, 256, 0, stream>>>(inv0, offs, fill, order, N);
    k_pool<<<MC, 256, 0, stream>>>(h, order, offs, cnt_i, sum0, cnt0, M0);
    k_rollup<<<(MC * DD) / 256, 256, 0, stream>>>(sum0, cnt0, parent10, sum1, cnt1, M0, MC);
    k_rollup<<<(512 * DD) / 256, 256, 0, stream>>>(sum1, cnt1, parent21, sum2, cnt2, M1, 512);
    k_finalize<<<(NS * MC * DD) / 256, 256, 0, stream>>>(macro, counts, M0, M1, M2);
    k_b0t<<<64, 256, 0, stream>>>(Wf, B0T);
    k_qkv<<<dim3(MC / 8, NS), 256, 0, stream>>>(macro, Wqkv, bqkv, qkvb, M0, M1, M2);
    k_attn_part<<<dim3(MC / 64, NHH, NS * NSPLIT), 256, 0, stream>>>(qkvb, part_o, part_ml, M0, M1, M2);
    k_attn_comb<<<dim3(MC / 64, NHH, NS), 256, 0, stream>>>(part_o, part_ml, attno, M0, M1, M2);
    k_ln1<<<dim3(MC, NS), 128, 0, stream>>>(macro, attno, Wo, bo, ln1s, ln1b, x1, M0, M1, M2);
    k_ffn<<<dim3(MC, NS), 256, 0, stream>>>(x1, W1, b1, W2, b2, ln2s, ln2b, x2, M0, M1, M2);
    k_yproj<<<dim3(MC, NS), 128, 0, stream>>>(x2, Wf, yb, M0, M1, M2);
    k_final<<<2048, 256, 0, stream>>>(h, B0T, yb, inv0, inv1, inv2, bf, (float*)d_out, N);
}